// Round 1
// 1123.498 us; speedup vs baseline: 1.3845x; 1.3845x over previous
//
#include <hip/hip_runtime.h>
#include <math.h>
#include <type_traits>

#define BB 20
#define CC 60
#define HH 264
#define WW 264
#define HWW (HH * WW)

typedef __attribute__((ext_vector_type(8))) short short8;
typedef __attribute__((ext_vector_type(16))) float f32x16;

static __device__ __forceinline__ ushort bf16_rne(float f) {
    unsigned u = __float_as_uint(f);
    u += 0x7FFFu + ((u >> 16) & 1u);
    return (ushort)(u >> 16);
}
static __device__ __forceinline__ void bf16_split(float f, ushort& h, ushort& l) {
    unsigned u = __float_as_uint(f);
    unsigned r = (u + (0x7FFFu + ((u >> 16) & 1u))) & 0xFFFF0000u;
    h = (ushort)(r >> 16);
    float res = f - __uint_as_float(r);
    l = bf16_rne(res);
}

// ---------------------------------------------------------------------------
// Kernel 1: adaptive avg-pool to 3x3 (exact 88x88 block means) -- unchanged
// ---------------------------------------------------------------------------
__global__ __launch_bounds__(256) void gap_kernel(const float* __restrict__ x,
                                                  float* __restrict__ x_gap) {
    const int bc = blockIdx.x;
    const float* xp = x + (size_t)bc * HWW;
    const int tid = threadIdx.x;

    __shared__ float red[3][128];
    for (int i = tid; i < 3 * 128; i += 256) ((float*)red)[i] = 0.f;
    __syncthreads();

    const int gw0 = tid / 88;
    const int p0  = tid - 88 * gw0;

    for (int gh = 0; gh < 3; ++gh) {
        float a0 = 0.f, a1 = 0.f;
        const int h0 = gh * 88;
        for (int h = h0; h < h0 + 88; ++h) {
            const float* row = xp + h * WW;
            a0 += row[tid];
            if (tid < 8) a1 += row[256 + tid];
        }
        red[gw0][p0] = a0;
        if (tid < 8) red[2][80 + tid] = a1;
        __syncthreads();
        if (tid < 192) {
            const int gw = tid >> 6, c = tid & 63;
            float v = red[gw][c] + red[gw][c + 64];
            for (int off = 32; off; off >>= 1) v += __shfl_down(v, off);
            if (c == 0) x_gap[bc * 9 + gh * 3 + gw] = v * (1.0f / 7744.0f);
        }
        __syncthreads();
    }
}

// ---------------------------------------------------------------------------
// Kernel 2: build packed bf16 hi/lo filter Gpk, frag-major for 32x32x16 MFMA.
// Layout: Gpk[((ks*2 + mg)*2 + s)*1024B + lane*16B + j*2B]
//   ks = tap*4 + q (q = 16-channel quarter), mg = o-half, s = hi/lo
//   element (lane,j): o = mg*32 + (lane&31), c = q*16 + (lane>>5)*8 + j
// grid = 9 blocks (one per tap), 256 threads
// ---------------------------------------------------------------------------
__global__ __launch_bounds__(256) void filt_kernel(
    const float* __restrict__ xg,
    const float* __restrict__ w1, const float* __restrict__ b1,
    const float* __restrict__ w2, const float* __restrict__ b2,
    const float* __restrict__ w3, const float* __restrict__ b3,
    const float* __restrict__ p1, const float* __restrict__ p2,
    const float* __restrict__ p3,
    const float* __restrict__ w_out, ushort* __restrict__ Gpk) {
    const int tap = blockIdx.x;
    const int tid = threadIdx.x;
    __shared__ float t[3][20][20];             // [g][oc][ic]

    for (int i = tid; i < 3 * 20 * 20; i += 256) {
        const int g = i / 400;
        const int rem = i - g * 400;
        const int oc = rem / 20;
        const int ic = rem - oc * 20;
        const float* wg = (g == 0) ? w1 : (g == 1) ? w2 : w3;
        const float* bg = (g == 0) ? b1 : (g == 1) ? b2 : b3;
        const float pg  = (g == 0) ? p1[0] : (g == 1) ? p2[0] : p3[0];
        float s = bg[ic];
        for (int c = 0; c < 60; ++c)
            s += xg[(oc * 60 + c) * 9 + tap] * wg[ic * 60 + c];
        t[g][oc][ic] = tanhf(pg * s);
    }
    __syncthreads();

    for (int idx = tid; idx < 4096; idx += 256) {
        const int j    = idx & 7;
        const int lane = (idx >> 3) & 63;
        const int mg   = (idx >> 9) & 1;
        const int q    = idx >> 10;
        const int c = q * 16 + ((lane >> 5) << 3) + j;
        const int o = mg * 32 + (lane & 31);
        float val = 0.f;
        if (c < 60 && o < 60) {
            const int g = c / 20;
            const int ic = c - 20 * g;
            #pragma unroll
            for (int oc = 0; oc < 20; ++oc)
                val += w_out[o * 60 + 20 * g + oc] * t[g][oc][ic];
        }
        ushort h, l;
        bf16_split(val, h, l);
        const int ks = tap * 4 + q;
        const size_t base = (size_t)(ks * 4 + mg * 2) * 512 + lane * 8 + j;
        Gpk[base] = h;          // s = 0 (hi)
        Gpk[base + 512] = l;    // s = 1 (lo)
    }
}

// ---------------------------------------------------------------------------
// Kernel 3: MFMA implicit-GEMM conv, bf16 hi/lo 3-pass split.
// Per block: one batch, 16x16 pixel tile, all 64 channels (60 + pad) staged
// once as hi/lo bf16 in LDS, channel-minor groups of 8 (B-frag friendly).
// 8 waves = (K-half kh x pixel-quad nq); each wave: Mf=2 (all 64 o) x Nf=2
// (64 pixels). K-halves reduced through LDS at the end.
// ---------------------------------------------------------------------------
#define TILE 16
#define TILES 17
#define NBLK (BB * TILES * TILES)
#define XS_LO 41472            /* byte offset of lo region: 8*324*16 */
#define SMEM_BYTES 82944       /* 16 groups * 324 pix * 16 B */

__global__ __launch_bounds__(512, 2) void conv_kernel(
    const float* __restrict__ x, const ushort* __restrict__ Gpk,
    const float* __restrict__ b_out, float* __restrict__ out) {
    extern __shared__ char sm[];

    const int blk = blockIdx.x;
    const int b   = blk / (TILES * TILES);
    const int tt  = blk - b * (TILES * TILES);
    const int ty0 = (tt / TILES) * TILE;
    const int tx0 = (tt - (tt / TILES) * TILES) * TILE;
    const int tid = threadIdx.x;

    // ---- stage x tile: 18x18 halo, 64 channels, hi/lo bf16 ----
    const float* xb = x + (size_t)b * CC * HWW;
    for (int i = tid; i < 324 * 16; i += 512) {
        const int cq  = i / 324;           // channel quad 0..15
        const int p   = i - cq * 324;      // pixel slot 0..323
        const int r   = p / 18;
        const int col = p - r * 18;
        const int gh = ty0 - 1 + r;
        const int gw = tx0 - 1 + col;
        const int c0 = cq * 4;
        float v0 = 0.f, v1 = 0.f, v2 = 0.f, v3 = 0.f;
        if (((unsigned)gh < HH) && ((unsigned)gw < WW) && (c0 < 60)) {
            const float* xp = xb + (size_t)c0 * HWW + gh * WW + gw;
            v0 = xp[0]; v1 = xp[HWW]; v2 = xp[2 * HWW]; v3 = xp[3 * HWW];
        }
        ushort h0, h1, h2, h3, l0, l1, l2, l3;
        bf16_split(v0, h0, l0);
        bf16_split(v1, h1, l1);
        bf16_split(v2, h2, l2);
        bf16_split(v3, h3, l3);
        const int base = ((cq >> 1) * 324 + p) * 16 + (cq & 1) * 8;
        *(uint2*)(sm + base) =
            make_uint2((uint)h0 | ((uint)h1 << 16), (uint)h2 | ((uint)h3 << 16));
        *(uint2*)(sm + base + XS_LO) =
            make_uint2((uint)l0 | ((uint)l1 << 16), (uint)l2 | ((uint)l3 << 16));
    }
    __syncthreads();

    // ---- wave setup ----
    const int lane = tid & 63;
    const int w    = tid >> 6;
    const int kh   = w >> 2;               // K-half
    const int nq   = w & 3;                // pixel quad (rows 4nq..4nq+3)
    const int sel  = lane >> 5;            // k-subgroup
    const int n    = lane & 31;            // pixel within frag
    const int px   = n & 15;
    const int ry   = n >> 4;
    const int rb0  = nq * 4 + ry;
    const int rb1  = rb0 + 2;

    const char* bh0_base = sm + ((rb0 * 18 + px) << 4) + sel * 5184;
    const char* bh1_base = sm + ((rb1 * 18 + px) << 4) + sel * 5184;
    const char* bl0_base = bh0_base + XS_LO;
    const char* bl1_base = bh1_base + XS_LO;
    const ushort* ga = Gpk + (size_t)kh * 18 * 2048 + lane * 8;

    f32x16 acc[2][2];
    #pragma unroll
    for (int mg = 0; mg < 2; ++mg)
        #pragma unroll
        for (int i = 0; i < 2; ++i)
            #pragma unroll
            for (int e = 0; e < 16; ++e) acc[mg][i][e] = 0.f;

    auto kloop = [&](auto KS0C) {
        constexpr int KS0 = KS0C.value;
        #pragma unroll
        for (int t = 0; t < 18; ++t) {
            const int ks  = KS0 + t;           // compile-time after unroll
            const int q   = ks & 3;
            const int tap = ks >> 2;
            const int dy  = tap / 3;
            const int dx  = tap - 3 * dy;
            const int boff = q * 10368 + (dy * 18 + dx) * 16;  // literal

            short8 ah0 = *(const short8*)(ga + (size_t)t * 2048);
            short8 al0 = *(const short8*)(ga + (size_t)t * 2048 + 512);
            short8 ah1 = *(const short8*)(ga + (size_t)t * 2048 + 1024);
            short8 al1 = *(const short8*)(ga + (size_t)t * 2048 + 1536);
            short8 bh0 = *(const short8*)(bh0_base + boff);
            short8 bl0 = *(const short8*)(bl0_base + boff);
            short8 bh1 = *(const short8*)(bh1_base + boff);
            short8 bl1 = *(const short8*)(bl1_base + boff);

            acc[0][0] = __builtin_amdgcn_mfma_f32_32x32x16_bf16(ah0, bh0, acc[0][0], 0, 0, 0);
            acc[1][0] = __builtin_amdgcn_mfma_f32_32x32x16_bf16(ah1, bh0, acc[1][0], 0, 0, 0);
            acc[0][1] = __builtin_amdgcn_mfma_f32_32x32x16_bf16(ah0, bh1, acc[0][1], 0, 0, 0);
            acc[1][1] = __builtin_amdgcn_mfma_f32_32x32x16_bf16(ah1, bh1, acc[1][1], 0, 0, 0);
            acc[0][0] = __builtin_amdgcn_mfma_f32_32x32x16_bf16(al0, bh0, acc[0][0], 0, 0, 0);
            acc[1][0] = __builtin_amdgcn_mfma_f32_32x32x16_bf16(al1, bh0, acc[1][0], 0, 0, 0);
            acc[0][1] = __builtin_amdgcn_mfma_f32_32x32x16_bf16(al0, bh1, acc[0][1], 0, 0, 0);
            acc[1][1] = __builtin_amdgcn_mfma_f32_32x32x16_bf16(al1, bh1, acc[1][1], 0, 0, 0);
            acc[0][0] = __builtin_amdgcn_mfma_f32_32x32x16_bf16(ah0, bl0, acc[0][0], 0, 0, 0);
            acc[1][0] = __builtin_amdgcn_mfma_f32_32x32x16_bf16(ah1, bl0, acc[1][0], 0, 0, 0);
            acc[0][1] = __builtin_amdgcn_mfma_f32_32x32x16_bf16(ah0, bl1, acc[0][1], 0, 0, 0);
            acc[1][1] = __builtin_amdgcn_mfma_f32_32x32x16_bf16(ah1, bl1, acc[1][1], 0, 0, 0);
        }
    };
    if (kh == 0) kloop(std::integral_constant<int, 0>{});
    else         kloop(std::integral_constant<int, 18>{});

    // ---- K-split reduction through LDS (reuses x region) ----
    __syncthreads();
    if (kh == 1) {
        #pragma unroll
        for (int mg = 0; mg < 2; ++mg)
            #pragma unroll
            for (int i = 0; i < 2; ++i) {
                char* p = sm + ((((nq * 2 + i) * 2 + mg) * 64 + lane) << 6);
                *(float4*)(p) =
                    make_float4(acc[mg][i][0], acc[mg][i][1], acc[mg][i][2], acc[mg][i][3]);
                *(float4*)(p + 16) =
                    make_float4(acc[mg][i][4], acc[mg][i][5], acc[mg][i][6], acc[mg][i][7]);
                *(float4*)(p + 32) =
                    make_float4(acc[mg][i][8], acc[mg][i][9], acc[mg][i][10], acc[mg][i][11]);
                *(float4*)(p + 48) =
                    make_float4(acc[mg][i][12], acc[mg][i][13], acc[mg][i][14], acc[mg][i][15]);
            }
    }
    __syncthreads();

    if (kh == 0) {
        const int pxg = tx0 + px;
        const bool okx = pxg < WW;
        #pragma unroll
        for (int mg = 0; mg < 2; ++mg)
            #pragma unroll
            for (int i = 0; i < 2; ++i) {
                const char* p = sm + ((((nq * 2 + i) * 2 + mg) * 64 + lane) << 6);
                const float4 r0 = *(const float4*)(p);
                const float4 r1 = *(const float4*)(p + 16);
                const float4 r2 = *(const float4*)(p + 32);
                const float4 r3 = *(const float4*)(p + 48);
                const float pr[16] = {r0.x, r0.y, r0.z, r0.w, r1.x, r1.y, r1.z, r1.w,
                                      r2.x, r2.y, r2.z, r2.w, r3.x, r3.y, r3.z, r3.w};
                const int py = ty0 + nq * 4 + 2 * i + ry;
                if (py < HH && okx) {
                    const size_t pbase = (size_t)b * 60 * HWW + (size_t)py * WW + pxg;
                    #pragma unroll
                    for (int e = 0; e < 16; ++e) {
                        const int o = mg * 32 + (e & 3) + 8 * (e >> 2) + 4 * sel;
                        if (o < 60)
                            out[pbase + (size_t)o * HWW] = acc[mg][i][e] + pr[e] + b_out[o];
                    }
                }
            }
    }
}

// ---------------------------------------------------------------------------
extern "C" void kernel_launch(void* const* d_in, const int* in_sizes, int n_in,
                              void* d_out, int out_size, void* d_ws, size_t ws_size,
                              hipStream_t stream) {
    const float* x     = (const float*)d_in[0];
    const float* w1    = (const float*)d_in[1];
    const float* b1    = (const float*)d_in[2];
    const float* w2    = (const float*)d_in[3];
    const float* b2    = (const float*)d_in[4];
    const float* w3    = (const float*)d_in[5];
    const float* b3    = (const float*)d_in[6];
    const float* p1    = (const float*)d_in[7];
    const float* p2    = (const float*)d_in[8];
    const float* p3    = (const float*)d_in[9];
    const float* w_out = (const float*)d_in[10];
    const float* b_out = (const float*)d_in[11];
    float* out = (float*)d_out;

    float* ws   = (float*)d_ws;
    float* xg   = ws;                        // 10800 floats
    ushort* Gpk = (ushort*)(ws + 10800);     // 73728 ushorts = 147456 B

    static int attr_done = 0;
    if (!attr_done) {
        hipFuncSetAttribute((const void*)conv_kernel,
                            hipFuncAttributeMaxDynamicSharedMemorySize, SMEM_BYTES);
        attr_done = 1;
    }

    gap_kernel<<<BB * CC, 256, 0, stream>>>(x, xg);
    filt_kernel<<<9, 256, 0, stream>>>(xg, w1, b1, w2, b2, w3, b3,
                                       p1, p2, p3, w_out, Gpk);
    conv_kernel<<<NBLK, 512, SMEM_BYTES, stream>>>(x, Gpk, b_out, out);
}

// Round 2
// 1060.246 us; speedup vs baseline: 1.4671x; 1.0597x over previous
//
#include <hip/hip_runtime.h>
#include <math.h>
#include <type_traits>

#define BB 20
#define CC 60
#define HH 264
#define WW 264
#define HWW (HH * WW)

typedef __attribute__((ext_vector_type(8))) short short8;
typedef __attribute__((ext_vector_type(16))) float f32x16;

static __device__ __forceinline__ ushort bf16_rne(float f) {
    unsigned u = __float_as_uint(f);
    u += 0x7FFFu + ((u >> 16) & 1u);
    return (ushort)(u >> 16);
}
static __device__ __forceinline__ void bf16_split(float f, ushort& h, ushort& l) {
    unsigned u = __float_as_uint(f);
    unsigned r = (u + (0x7FFFu + ((u >> 16) & 1u))) & 0xFFFF0000u;
    h = (ushort)(r >> 16);
    float res = f - __uint_as_float(r);
    l = bf16_rne(res);
}

// ---------------------------------------------------------------------------
// Kernel 1: adaptive avg-pool to 3x3 (exact 88x88 block means) -- unchanged
// ---------------------------------------------------------------------------
__global__ __launch_bounds__(256) void gap_kernel(const float* __restrict__ x,
                                                  float* __restrict__ x_gap) {
    const int bc = blockIdx.x;
    const float* xp = x + (size_t)bc * HWW;
    const int tid = threadIdx.x;

    __shared__ float red[3][128];
    for (int i = tid; i < 3 * 128; i += 256) ((float*)red)[i] = 0.f;
    __syncthreads();

    const int gw0 = tid / 88;
    const int p0  = tid - 88 * gw0;

    for (int gh = 0; gh < 3; ++gh) {
        float a0 = 0.f, a1 = 0.f;
        const int h0 = gh * 88;
        for (int h = h0; h < h0 + 88; ++h) {
            const float* row = xp + h * WW;
            a0 += row[tid];
            if (tid < 8) a1 += row[256 + tid];
        }
        red[gw0][p0] = a0;
        if (tid < 8) red[2][80 + tid] = a1;
        __syncthreads();
        if (tid < 192) {
            const int gw = tid >> 6, c = tid & 63;
            float v = red[gw][c] + red[gw][c + 64];
            for (int off = 32; off; off >>= 1) v += __shfl_down(v, off);
            if (c == 0) x_gap[bc * 9 + gh * 3 + gw] = v * (1.0f / 7744.0f);
        }
        __syncthreads();
    }
}

// ---------------------------------------------------------------------------
// Kernel 2: build packed bf16 hi/lo filter Gpk, frag-major for 32x32x16 MFMA.
// Layout: Gpk[((ks*2 + mg)*2 + s)*1024B + lane*16B + j*2B]
//   ks = tap*4 + q (q = 16-channel quarter), mg = o-half, s = hi/lo
//   element (lane,j): o = mg*32 + (lane&31), c = q*16 + (lane>>5)*8 + j
// ---------------------------------------------------------------------------
__global__ __launch_bounds__(256) void filt_kernel(
    const float* __restrict__ xg,
    const float* __restrict__ w1, const float* __restrict__ b1,
    const float* __restrict__ w2, const float* __restrict__ b2,
    const float* __restrict__ w3, const float* __restrict__ b3,
    const float* __restrict__ p1, const float* __restrict__ p2,
    const float* __restrict__ p3,
    const float* __restrict__ w_out, ushort* __restrict__ Gpk) {
    const int tap = blockIdx.x;
    const int tid = threadIdx.x;
    __shared__ float t[3][20][20];             // [g][oc][ic]

    for (int i = tid; i < 3 * 20 * 20; i += 256) {
        const int g = i / 400;
        const int rem = i - g * 400;
        const int oc = rem / 20;
        const int ic = rem - oc * 20;
        const float* wg = (g == 0) ? w1 : (g == 1) ? w2 : w3;
        const float* bg = (g == 0) ? b1 : (g == 1) ? b2 : b3;
        const float pg  = (g == 0) ? p1[0] : (g == 1) ? p2[0] : p3[0];
        float s = bg[ic];
        for (int c = 0; c < 60; ++c)
            s += xg[(oc * 60 + c) * 9 + tap] * wg[ic * 60 + c];
        t[g][oc][ic] = tanhf(pg * s);
    }
    __syncthreads();

    for (int idx = tid; idx < 4096; idx += 256) {
        const int j    = idx & 7;
        const int lane = (idx >> 3) & 63;
        const int mg   = (idx >> 9) & 1;
        const int q    = idx >> 10;
        const int c = q * 16 + ((lane >> 5) << 3) + j;
        const int o = mg * 32 + (lane & 31);
        float val = 0.f;
        if (c < 60 && o < 60) {
            const int g = c / 20;
            const int ic = c - 20 * g;
            #pragma unroll
            for (int oc = 0; oc < 20; ++oc)
                val += w_out[o * 60 + 20 * g + oc] * t[g][oc][ic];
        }
        ushort h, l;
        bf16_split(val, h, l);
        const int ks = tap * 4 + q;
        const size_t base = (size_t)(ks * 4 + mg * 2) * 512 + lane * 8 + j;
        Gpk[base] = h;          // s = 0 (hi)
        Gpk[base + 512] = l;    // s = 1 (lo)
    }
}

// ---------------------------------------------------------------------------
// Kernel 3: MFMA implicit-GEMM conv, bf16 hi/lo 3-pass split.
// Tile 16 cols x 8 rows per block (halo 18x10 = 180 px), 256 threads
// (4 waves = 2 K-halves x 2 row-quads). LDS = 46080 B -> 3 blocks/CU
// (12 waves/CU) so stage phases of one block overlap MFMA of others.
// ---------------------------------------------------------------------------
#define TX 16
#define TY 8
#define TSX 17                 /* ceil(264/16) */
#define TSY 33                 /* 264/8 */
#define NBLK (BB * TSX * TSY)
#define PIX 180                /* 10 rows x 18 cols halo */
#define GRP 2880               /* bytes per 8-ch group: 180*16 */
#define QSTR 5760              /* bytes per 16-ch quarter */
#define XS_LO 23040            /* lo region offset: 8 groups * GRP */
#define SMEM_BYTES 46080       /* 16 groups * GRP */

__global__ __launch_bounds__(256, 3) void conv_kernel(
    const float* __restrict__ x, const ushort* __restrict__ Gpk,
    const float* __restrict__ b_out, float* __restrict__ out) {
    extern __shared__ char sm[];

    const int blk = blockIdx.x;
    const int b   = blk / (TSX * TSY);
    const int tt  = blk - b * (TSX * TSY);
    const int tyi = tt / TSX;
    const int txi = tt - tyi * TSX;
    const int ty0 = tyi * TY;
    const int tx0 = txi * TX;
    const int tid = threadIdx.x;

    // ---- stage x tile: 10x18 halo, 64 channel slots, hi/lo bf16 ----
    const float* xb = x + (size_t)b * CC * HWW;
    for (int i = tid; i < PIX * 16; i += 256) {
        const int cq  = i / PIX;           // channel quad 0..15
        const int p   = i - cq * PIX;      // pixel slot 0..179
        const int r   = p / 18;
        const int col = p - r * 18;
        const int gh = ty0 - 1 + r;
        const int gw = tx0 - 1 + col;
        const int c0 = cq * 4;
        float v0 = 0.f, v1 = 0.f, v2 = 0.f, v3 = 0.f;
        if (((unsigned)gh < HH) && ((unsigned)gw < WW) && (c0 < 60)) {
            const float* xp = xb + (size_t)c0 * HWW + gh * WW + gw;
            v0 = xp[0]; v1 = xp[HWW]; v2 = xp[2 * HWW]; v3 = xp[3 * HWW];
        }
        ushort h0, h1, h2, h3, l0, l1, l2, l3;
        bf16_split(v0, h0, l0);
        bf16_split(v1, h1, l1);
        bf16_split(v2, h2, l2);
        bf16_split(v3, h3, l3);
        const int base = ((cq >> 1) * PIX + p) * 16 + (cq & 1) * 8;
        *(uint2*)(sm + base) =
            make_uint2((uint)h0 | ((uint)h1 << 16), (uint)h2 | ((uint)h3 << 16));
        *(uint2*)(sm + base + XS_LO) =
            make_uint2((uint)l0 | ((uint)l1 << 16), (uint)l2 | ((uint)l3 << 16));
    }
    __syncthreads();

    // ---- wave setup ----
    const int lane = tid & 63;
    const int w    = tid >> 6;             // 0..3
    const int kh   = w >> 1;               // K-half
    const int nq   = w & 1;                // row quad (rows 4nq..4nq+3)
    const int sel  = lane >> 5;            // k-subgroup
    const int n    = lane & 31;            // pixel within frag
    const int px   = n & 15;
    const int ry   = n >> 4;
    const int rb0  = nq * 4 + ry;
    const int rb1  = rb0 + 2;

    const char* bh0_base = sm + ((rb0 * 18 + px) << 4) + sel * GRP;
    const char* bh1_base = sm + ((rb1 * 18 + px) << 4) + sel * GRP;
    const char* bl0_base = bh0_base + XS_LO;
    const char* bl1_base = bh1_base + XS_LO;
    const ushort* ga = Gpk + (size_t)kh * 18 * 2048 + lane * 8;

    f32x16 acc[2][2];
    #pragma unroll
    for (int mg = 0; mg < 2; ++mg)
        #pragma unroll
        for (int i = 0; i < 2; ++i)
            #pragma unroll
            for (int e = 0; e < 16; ++e) acc[mg][i][e] = 0.f;

    auto kloop = [&](auto KS0C) {
        constexpr int KS0 = KS0C.value;
        #pragma unroll
        for (int t = 0; t < 18; ++t) {
            const int ks  = KS0 + t;           // compile-time after unroll
            const int q   = ks & 3;
            const int tap = ks >> 2;
            const int dy  = tap / 3;
            const int dx  = tap - 3 * dy;
            const int boff = q * QSTR + (dy * 18 + dx) * 16;  // literal

            short8 ah0 = *(const short8*)(ga + (size_t)t * 2048);
            short8 al0 = *(const short8*)(ga + (size_t)t * 2048 + 512);
            short8 ah1 = *(const short8*)(ga + (size_t)t * 2048 + 1024);
            short8 al1 = *(const short8*)(ga + (size_t)t * 2048 + 1536);
            short8 bh0 = *(const short8*)(bh0_base + boff);
            short8 bl0 = *(const short8*)(bl0_base + boff);
            short8 bh1 = *(const short8*)(bh1_base + boff);
            short8 bl1 = *(const short8*)(bl1_base + boff);

            acc[0][0] = __builtin_amdgcn_mfma_f32_32x32x16_bf16(ah0, bh0, acc[0][0], 0, 0, 0);
            acc[1][0] = __builtin_amdgcn_mfma_f32_32x32x16_bf16(ah1, bh0, acc[1][0], 0, 0, 0);
            acc[0][1] = __builtin_amdgcn_mfma_f32_32x32x16_bf16(ah0, bh1, acc[0][1], 0, 0, 0);
            acc[1][1] = __builtin_amdgcn_mfma_f32_32x32x16_bf16(ah1, bh1, acc[1][1], 0, 0, 0);
            acc[0][0] = __builtin_amdgcn_mfma_f32_32x32x16_bf16(al0, bh0, acc[0][0], 0, 0, 0);
            acc[1][0] = __builtin_amdgcn_mfma_f32_32x32x16_bf16(al1, bh0, acc[1][0], 0, 0, 0);
            acc[0][1] = __builtin_amdgcn_mfma_f32_32x32x16_bf16(al0, bh1, acc[0][1], 0, 0, 0);
            acc[1][1] = __builtin_amdgcn_mfma_f32_32x32x16_bf16(al1, bh1, acc[1][1], 0, 0, 0);
            acc[0][0] = __builtin_amdgcn_mfma_f32_32x32x16_bf16(ah0, bl0, acc[0][0], 0, 0, 0);
            acc[1][0] = __builtin_amdgcn_mfma_f32_32x32x16_bf16(ah1, bl0, acc[1][0], 0, 0, 0);
            acc[0][1] = __builtin_amdgcn_mfma_f32_32x32x16_bf16(ah0, bl1, acc[0][1], 0, 0, 0);
            acc[1][1] = __builtin_amdgcn_mfma_f32_32x32x16_bf16(ah1, bl1, acc[1][1], 0, 0, 0);
        }
    };
    if (kh == 0) kloop(std::integral_constant<int, 0>{});
    else         kloop(std::integral_constant<int, 18>{});

    // ---- K-split reduction through LDS (reuses x region, 32 KB) ----
    __syncthreads();
    if (kh == 1) {
        #pragma unroll
        for (int mg = 0; mg < 2; ++mg)
            #pragma unroll
            for (int i = 0; i < 2; ++i) {
                char* p = sm + ((((nq * 2 + i) * 2 + mg) * 64 + lane) << 6);
                *(float4*)(p) =
                    make_float4(acc[mg][i][0], acc[mg][i][1], acc[mg][i][2], acc[mg][i][3]);
                *(float4*)(p + 16) =
                    make_float4(acc[mg][i][4], acc[mg][i][5], acc[mg][i][6], acc[mg][i][7]);
                *(float4*)(p + 32) =
                    make_float4(acc[mg][i][8], acc[mg][i][9], acc[mg][i][10], acc[mg][i][11]);
                *(float4*)(p + 48) =
                    make_float4(acc[mg][i][12], acc[mg][i][13], acc[mg][i][14], acc[mg][i][15]);
            }
    }
    __syncthreads();

    if (kh == 0) {
        const int pxg = tx0 + px;
        const bool okx = pxg < WW;
        #pragma unroll
        for (int mg = 0; mg < 2; ++mg)
            #pragma unroll
            for (int i = 0; i < 2; ++i) {
                const char* p = sm + ((((nq * 2 + i) * 2 + mg) * 64 + lane) << 6);
                const float4 r0 = *(const float4*)(p);
                const float4 r1 = *(const float4*)(p + 16);
                const float4 r2 = *(const float4*)(p + 32);
                const float4 r3 = *(const float4*)(p + 48);
                const float pr[16] = {r0.x, r0.y, r0.z, r0.w, r1.x, r1.y, r1.z, r1.w,
                                      r2.x, r2.y, r2.z, r2.w, r3.x, r3.y, r3.z, r3.w};
                const int py = ty0 + nq * 4 + 2 * i + ry;
                if (py < HH && okx) {
                    const size_t pbase = (size_t)b * 60 * HWW + (size_t)py * WW + pxg;
                    #pragma unroll
                    for (int e = 0; e < 16; ++e) {
                        const int o = mg * 32 + (e & 3) + 8 * (e >> 2) + 4 * sel;
                        if (o < 60)
                            out[pbase + (size_t)o * HWW] = acc[mg][i][e] + pr[e] + b_out[o];
                    }
                }
            }
    }
}

// ---------------------------------------------------------------------------
extern "C" void kernel_launch(void* const* d_in, const int* in_sizes, int n_in,
                              void* d_out, int out_size, void* d_ws, size_t ws_size,
                              hipStream_t stream) {
    const float* x     = (const float*)d_in[0];
    const float* w1    = (const float*)d_in[1];
    const float* b1    = (const float*)d_in[2];
    const float* w2    = (const float*)d_in[3];
    const float* b2    = (const float*)d_in[4];
    const float* w3    = (const float*)d_in[5];
    const float* b3    = (const float*)d_in[6];
    const float* p1    = (const float*)d_in[7];
    const float* p2    = (const float*)d_in[8];
    const float* p3    = (const float*)d_in[9];
    const float* w_out = (const float*)d_in[10];
    const float* b_out = (const float*)d_in[11];
    float* out = (float*)d_out;

    float* ws   = (float*)d_ws;
    float* xg   = ws;                        // 10800 floats
    ushort* Gpk = (ushort*)(ws + 10800);     // 73728 ushorts = 147456 B

    static int attr_done = 0;
    if (!attr_done) {
        hipFuncSetAttribute((const void*)conv_kernel,
                            hipFuncAttributeMaxDynamicSharedMemorySize, SMEM_BYTES);
        attr_done = 1;
    }

    gap_kernel<<<BB * CC, 256, 0, stream>>>(x, xg);
    filt_kernel<<<9, 256, 0, stream>>>(xg, w1, b1, w2, b2, w3, b3,
                                       p1, p2, p3, w_out, Gpk);
    conv_kernel<<<NBLK, 256, SMEM_BYTES, stream>>>(x, Gpk, b_out, out);
}